// Round 9
// baseline (194.306 us; speedup 1.0000x reference)
//
#include <hip/hip_runtime.h>
#include <hip/hip_bf16.h>

// Problem constants (AttentionLayer: B=16, S=2048, D=512, H=64)
#define B_ 16
#define S_ 2048
#define D_ 512
#define H_ 64

typedef __attribute__((ext_vector_type(8))) short short8;    // 8 x bf16 (4 VGPRs)
typedef __attribute__((ext_vector_type(16))) float f32x16;   // 32x32 MFMA accumulator

static __device__ __forceinline__ short f2bf(float f) {
  union { __hip_bfloat16 h; short s; } u;
  u.h = __float2bfloat16(f);   // RNE
  return u.s;
}
static __device__ __forceinline__ float b2f(short s) {
  union { float f; unsigned u; } x;
  x.u = ((unsigned)(unsigned short)s) << 16;
  return x.f;
}
// pack two fp32 -> one u32 of 2 bf16 (RNE).  src0 -> low 16 bits.
static __device__ __forceinline__ unsigned cvtpk(float lo, float hi) {
  unsigned r;
  asm("v_cvt_pk_bf16_f32 %0, %1, %2" : "=v"(r) : "v"(lo), "v"(hi));
  return r;
}
// NOTE (r7/r8 lesson): v_permlane32_swap_b32 via "+v","+v" inline asm is
// UNSAFE when both operands carry the same value — regalloc may assign one
// VGPR to both, making the half-swap undefined.  Reductions here use
// __shfl_xor (r6-proven) until a defined-semantics builtin path is validated.

// ---------------------------------------------------------------------------
// Kernel 0: transpose + convert weights to bf16; combined bias[192].
// Wq/bq PRE-SCALED by log2e/sqrt(H): QK^T scores land directly in the exp2
// domain.
// ---------------------------------------------------------------------------
__global__ void prep_weights(const float* __restrict__ Wq,
                             const float* __restrict__ Wk,
                             const float* __restrict__ Wv,
                             const float* __restrict__ bq,
                             const float* __restrict__ bk,
                             const float* __restrict__ bv,
                             short* __restrict__ Wt, float* __restrict__ biasAll) {
  int n = blockIdx.x;                       // 0..191
  const float* src  = (n < 64) ? Wq : (n < 128) ? Wk : Wv;
  const float* bsrc = (n < 64) ? bq : (n < 128) ? bk : bv;
  float scale = (n < 64) ? 0.18033688011112042f : 1.0f;  // log2(e)/sqrt(64)
  int col = n & 63;
  for (int k = threadIdx.x; k < D_; k += 256)
    Wt[n * D_ + k] = f2bf(src[k * H_ + col] * scale);
  if (threadIdx.x == 0) biasAll[n] = bsrc[col] * scale;
}

// ---------------------------------------------------------------------------
// Kernel 1: fused QKV projection, LDS-staged (structure validated r6).
// ---------------------------------------------------------------------------
__global__ __launch_bounds__(384) void qkv_proj(
    const float* __restrict__ in, const short* __restrict__ Wt,
    const float* __restrict__ biasAll,
    short* __restrict__ Qb, short* __restrict__ Kb, short* __restrict__ Vt) {
  int tid = threadIdx.x;
  int w = tid >> 6, l = tid & 63, cl = l & 31, h = l >> 5;
  int rowbase = blockIdx.x * 32;

  __shared__ short alds[16384];     // 32 KB: 32 rows x 1024 B, XOR-swizzled
  __shared__ short vtile[64][40];   // 5 KB transpose staging

  // ---- stage 32x512 fp32 -> bf16 swizzled LDS ----
  for (int i = tid; i < 2048; i += 384) {
    int r = i >> 6, c8 = i & 63;
    const float* sp = in + (size_t)(rowbase + r) * D_ + c8 * 8;
    float4 f0 = *reinterpret_cast<const float4*>(sp);
    float4 f1 = *reinterpret_cast<const float4*>(sp + 4);
    union { unsigned u[4]; short8 v; } pk;
    pk.u[0] = cvtpk(f0.x, f0.y); pk.u[1] = cvtpk(f0.z, f0.w);
    pk.u[2] = cvtpk(f1.x, f1.y); pk.u[3] = cvtpk(f1.z, f1.w);
    int addr = r * 1024 + ((c8 * 16) ^ ((r & 7) << 4));
    *reinterpret_cast<short8*>(reinterpret_cast<char*>(alds) + addr) = pk.v;
  }
  __syncthreads();

  // ---- MFMA: A = input rows (lane cl), B = Wt row (out-col) w*32+cl ----
  const short* wb = Wt + (w * 32 + cl) * D_ + h * 8;
  f32x16 acc;
#pragma unroll
  for (int i = 0; i < 16; ++i) acc[i] = 0.f;
  int abase = cl * 1024, axor = (cl & 7) << 4;
#pragma unroll 8
  for (int ks = 0; ks < 32; ++ks) {
    short8 af = *reinterpret_cast<const short8*>(
        reinterpret_cast<char*>(alds) + abase + ((ks * 32 + h * 16) ^ axor));
    short8 bf = *reinterpret_cast<const short8*>(wb + ks * 16);
    acc = __builtin_amdgcn_mfma_f32_32x32x16_bf16(af, bf, acc, 0, 0, 0);
  }

  float bias = biasAll[w * 32 + cl];
  // C/D: out-col = cl, input-row rl = (i&3)+8*(i>>2)+4*h   [validated r5/r6]
  if (w < 4) {
    short* dst = (w < 2) ? Qb : Kb;
    int cb = (w & 1) * 32 + cl;
#pragma unroll
    for (int i = 0; i < 16; ++i) {
      int rl = (i & 3) + 8 * (i >> 2) + 4 * h;
      dst[(size_t)(rowbase + rl) * H_ + cb] = f2bf(acc[i] + bias);
    }
  } else {
#pragma unroll
    for (int i = 0; i < 16; ++i) {
      int rl = (i & 3) + 8 * (i >> 2) + 4 * h;
      vtile[(w - 4) * 32 + cl][rl] = f2bf(acc[i] + bias);
    }
  }
  __syncthreads();
  // ---- coalesced transposed V store ----
  if (tid < 256) {
    int hh = tid >> 2, ch = tid & 3;
    short8 v = *reinterpret_cast<const short8*>(&vtile[hh][ch * 8]);
    int b = rowbase >> 11, s0 = rowbase & (S_ - 1);
    *reinterpret_cast<short8*>(Vt + ((size_t)b * H_ + hh) * S_ + s0 + ch * 8) = v;
  }
}

// ---------------------------------------------------------------------------
// Kernel 2: flash attention + mean pool.  EXACT r6 structure (last passing)
// with exactly two audited-safe changes: (a) exp2f libcall -> native
// v_exp_f32 (__builtin_amdgcn_exp2f), (b) V prefetched one iteration ahead
// like K.  Reductions and P-exchange use r6's proven __shfl_xor forms.
// Grid = B * (S/32) = 1024 blocks x 4 waves; wave w sweeps keys [w*512,+512).
// ---------------------------------------------------------------------------
__global__ __launch_bounds__(256) void attn_pool(
    const short* __restrict__ Qb, const short* __restrict__ Kb,
    const short* __restrict__ Vt, float* __restrict__ out) {
  int tid = threadIdx.x;
  int w = tid >> 6, l = tid & 63, q = l & 31, h = l >> 5;
  int qc = blockIdx.x & 63, b = blockIdx.x >> 6;
  size_t boff = (size_t)b * (S_ * H_);
  int qrow = qc * 32;

  // Q fragments (pre-scaled by log2e/sqrt(H) at projection time)
  short8 qa[4];
#pragma unroll
  for (int s4 = 0; s4 < 4; ++s4)
    qa[s4] = *reinterpret_cast<const short8*>(
        Qb + boff + (size_t)(qrow + q) * H_ + s4 * 16 + h * 8);

  f32x16 o0, o1;
#pragma unroll
  for (int i = 0; i < 16; ++i) { o0[i] = 0.f; o1[i] = 0.f; }
  float m = -INFINITY, lsum = 0.f;

  const short* vrow = Vt + ((size_t)b * H_ + q) * S_;

  // preload K/V tile 0
  short8 ka[4], va[4];
  {
    const short* kp = Kb + boff + (size_t)(w * 512 + q) * H_ + h * 8;
#pragma unroll
    for (int s4 = 0; s4 < 4; ++s4)
      ka[s4] = *reinterpret_cast<const short8*>(kp + s4 * 16);
    const short* vp = vrow + w * 512 + h * 8;
    va[0] = *reinterpret_cast<const short8*>(vp);
    va[1] = *reinterpret_cast<const short8*>(vp + 16);
    va[2] = *reinterpret_cast<const short8*>(vp + 32 * S_);
    va[3] = *reinterpret_cast<const short8*>(vp + 32 * S_ + 16);
  }

#pragma unroll
  for (int it = 0; it < 16; ++it) {
    int tbase = w * 512 + it * 32;

    // ---- prefetch K(it+1) AND V(it+1): full iteration of latency budget ----
    short8 kn[4], vn[4];
    if (it < 15) {
      const short* kp = Kb + boff + (size_t)(tbase + 32 + q) * H_ + h * 8;
#pragma unroll
      for (int s4 = 0; s4 < 4; ++s4)
        kn[s4] = *reinterpret_cast<const short8*>(kp + s4 * 16);
      const short* vp = vrow + tbase + 32 + h * 8;
      vn[0] = *reinterpret_cast<const short8*>(vp);
      vn[1] = *reinterpret_cast<const short8*>(vp + 16);
      vn[2] = *reinterpret_cast<const short8*>(vp + 32 * S_);
      vn[3] = *reinterpret_cast<const short8*>(vp + 32 * S_ + 16);
    }

    // ---- S^T[key][q] = K·Q^T (already in log2 domain) ----
    f32x16 st;
#pragma unroll
    for (int i = 0; i < 16; ++i) st[i] = 0.f;
    __builtin_amdgcn_s_setprio(1);
#pragma unroll
    for (int s4 = 0; s4 < 4; ++s4)
      st = __builtin_amdgcn_mfma_f32_32x32x16_bf16(ka[s4], qa[s4], st, 0, 0, 0);
    __builtin_amdgcn_s_setprio(0);

    // ---- lane-local online softmax with defer-max (T13, THR=8) ----
    float tm = st[0];
#pragma unroll
    for (int i = 1; i < 16; ++i) tm = fmaxf(tm, st[i]);
    tm = fmaxf(tm, __shfl_xor(tm, 32));
    if (__any(tm > m + 8.0f)) {
      float mn = fmaxf(m, tm);
      float al = __builtin_amdgcn_exp2f(m - mn);   // 0 on first tile
      lsum *= al;
#pragma unroll
      for (int i = 0; i < 16; ++i) { o0[i] *= al; o1[i] *= al; }
      m = mn;
    }
    float ts = 0.f;
    unsigned W[4][2];
#pragma unroll
    for (int t = 0; t < 4; ++t) {
      float p0 = __builtin_amdgcn_exp2f(st[4 * t + 0] - m);
      float p1 = __builtin_amdgcn_exp2f(st[4 * t + 1] - m);
      float p2 = __builtin_amdgcn_exp2f(st[4 * t + 2] - m);
      float p3 = __builtin_amdgcn_exp2f(st[4 * t + 3] - m);
      ts += (p0 + p1) + (p2 + p3);
      W[t][0] = cvtpk(p0, p1);
      W[t][1] = cvtpk(p2, p3);
    }
    ts += __shfl_xor(ts, 32);
    lsum += ts;

    // ---- P -> bf16 B-fragments in-register (r6-proven routing) ----
    short8 bf[2];
#pragma unroll
    for (int s = 0; s < 2; ++s) {
      unsigned k0 = h ? W[2 * s + 1][0] : W[2 * s][0];
      unsigned k1 = h ? W[2 * s + 1][1] : W[2 * s][1];
      unsigned s0 = h ? W[2 * s][0] : W[2 * s + 1][0];
      unsigned s1 = h ? W[2 * s][1] : W[2 * s + 1][1];
      unsigned r0 = (unsigned)__shfl_xor((int)s0, 32);
      unsigned r1 = (unsigned)__shfl_xor((int)s1, 32);
      union { unsigned u[4]; short8 v; } bb;
      bb.u[0] = h ? r0 : k0;
      bb.u[1] = h ? r1 : k1;
      bb.u[2] = h ? k0 : r0;
      bb.u[3] = h ? k1 : r1;
      bf[s] = bb.v;
    }

    // ---- O^T[dv][q] += V^T · P ----
    __builtin_amdgcn_s_setprio(1);
    o0 = __builtin_amdgcn_mfma_f32_32x32x16_bf16(va[0], bf[0], o0, 0, 0, 0);
    o0 = __builtin_amdgcn_mfma_f32_32x32x16_bf16(va[1], bf[1], o0, 0, 0, 0);
    o1 = __builtin_amdgcn_mfma_f32_32x32x16_bf16(va[2], bf[0], o1, 0, 0, 0);
    o1 = __builtin_amdgcn_mfma_f32_32x32x16_bf16(va[3], bf[1], o1, 0, 0, 0);
    __builtin_amdgcn_s_setprio(0);

    if (it < 15) {
#pragma unroll
      for (int s4 = 0; s4 < 4; ++s4) { ka[s4] = kn[s4]; va[s4] = vn[s4]; }
    }
  }

  // ---- cross-wave merge (rebase to m*=0, bf16 staging) + mean pool ----
  float sc = __builtin_amdgcn_exp2f(m);

  __shared__ short mo[4][64][34];   // 17408 B (bf16; +2 pad)
  __shared__ float mls[4][32];      // 512 B
  __shared__ float red[4][64];      // 1024 B
#pragma unroll
  for (int i = 0; i < 16; ++i) {
    int dv = (i & 3) + 8 * (i >> 2) + 4 * h;
    mo[w][dv][q] = f2bf(o0[i] * sc);
    mo[w][32 + dv][q] = f2bf(o1[i] * sc);
  }
  if (h == 0) mls[w][q] = lsum * sc;
  __syncthreads();

  int dv = tid & 63, qg = tid >> 6;
  float acc = 0.f;
#pragma unroll
  for (int j = 0; j < 8; ++j) {
    int qq = qg * 8 + j;
    float L = mls[0][qq] + mls[1][qq] + mls[2][qq] + mls[3][qq];
    float num = b2f(mo[0][dv][qq]) + b2f(mo[1][dv][qq]) +
                b2f(mo[2][dv][qq]) + b2f(mo[3][dv][qq]);
    acc += num / L;
  }
  red[qg][dv] = acc;
  __syncthreads();
  if (tid < 64) {
    float s = red[0][tid] + red[1][tid] + red[2][tid] + red[3][tid];
    atomicAdd(out + b * H_ + tid, s * (1.0f / (float)S_));
  }
}

// ---------------------------------------------------------------------------
extern "C" void kernel_launch(void* const* d_in, const int* in_sizes, int n_in,
                              void* d_out, int out_size, void* d_ws, size_t ws_size,
                              hipStream_t stream) {
  const float* in = (const float*)d_in[0];
  const float* Wq = (const float*)d_in[1];
  const float* bq = (const float*)d_in[2];
  const float* Wk = (const float*)d_in[3];
  const float* bk = (const float*)d_in[4];
  const float* Wv = (const float*)d_in[5];
  const float* bv = (const float*)d_in[6];
  float* out = (float*)d_out;

  char* ws = (char*)d_ws;
  short* Qb      = (short*)(ws);                                   // 4 MiB
  short* Kb      = (short*)(ws + (size_t)4 * 1024 * 1024);         // 4 MiB
  short* Vt      = (short*)(ws + (size_t)8 * 1024 * 1024);         // 4 MiB
  short* Wt      = (short*)(ws + (size_t)12 * 1024 * 1024);        // 192 KiB
  float* biasAll = (float*)(ws + (size_t)12 * 1024 * 1024 + 192 * 1024);  // 768 B
  // total workspace footprint: ~12.2 MiB (validated rounds 1/4/5/6)

  prep_weights<<<192, 256, 0, stream>>>(Wq, Wk, Wv, bq, bk, bv, Wt, biasAll);
  qkv_proj<<<1024, 384, 0, stream>>>(in, Wt, biasAll, Qb, Kb, Vt);
  hipMemsetAsync(d_out, 0, (size_t)out_size * sizeof(float), stream);
  attn_pool<<<1024, 256, 0, stream>>>(Qb, Kb, Vt, out);
}